// Round 1
// baseline (3189.371 us; speedup 1.0000x reference)
//
#include <hip/hip_runtime.h>
#include <math.h>

#define ND 256      // doc rows per sentence
#define NQ 512      // query rows
#define NF 50       // features
#define NFP 52      // padded row stride (floats), 208 B = 13*16 -> b128-aligned
#define JCH 64      // query-chunk rows
#define NCH (NQ / JCH)

// LDS float offsets
#define OFF_R1    0              // sen rows (256*52=13312); later t rows 256..511
#define OFF_R2    13312          // t rows 0..255 (13312)
#define OFF_SW1   26624          // senw1[256]
#define OFF_RMAX  26880          // rowmax[256]
#define OFF_RINV  27136          // rowinv[256]
#define OFF_CMAX  27392          // colmax[512]
#define OFF_CINV  27904          // colinv[512]
#define OFF_QT    28416          // qterm[512]
#define OFF_CHQ   28928          // raw query chunk (64*52=3328)
#define OFF_CHS   32256          // scaled (q*w3) chunk (3328)
#define LDS_FLOATS 35584         // 142336 B
#define OFF_STAGE OFF_CHQ        // 6656 floats >= 32 rows * 200

__device__ __forceinline__ float dot50(const float* __restrict__ a,
                                       const float* lb) {
    float d0 = 0.f, d1 = 0.f, d2 = 0.f, d3 = 0.f;
    #pragma unroll
    for (int k = 0; k < 48; k += 4) {
        d0 += a[k]     * lb[k];
        d1 += a[k + 1] * lb[k + 1];
        d2 += a[k + 2] * lb[k + 2];
        d3 += a[k + 3] * lb[k + 3];
    }
    d0 += a[48] * lb[48];
    d1 += a[49] * lb[49];
    return (d0 + d1) + (d2 + d3);
}

__launch_bounds__(256, 1)
__global__ void cross_attn_kernel(const float* __restrict__ query,
                                  const float* __restrict__ doc,
                                  const float* __restrict__ W,
                                  float* __restrict__ out)
{
    extern __shared__ float lds[];
    const int tid = threadIdx.x;
    const int s = blockIdx.x;
    const float* sen_g = doc + (size_t)s * (ND * NF);

    // ---------- setup: sen -> LDS (padded), qterm ----------
    for (int idx = tid; idx < ND * (NF / 2); idx += 256) {
        int r = idx / (NF / 2);
        int c = idx - r * (NF / 2);
        float2 v = ((const float2*)sen_g)[r * (NF / 2) + c];
        lds[OFF_R1 + r * NFP + 2 * c]     = v.x;
        lds[OFF_R1 + r * NFP + 2 * c + 1] = v.y;
    }
    for (int jj = tid; jj < NQ; jj += 256) {
        float acc = 0.f;
        #pragma unroll
        for (int k = 0; k < NF; ++k) acc += query[jj * NF + k] * W[NF + k];
        lds[OFF_QT + jj] = acc;
    }
    __syncthreads();

    // own sen row -> regs; senw1
    float senreg[NF];
    #pragma unroll
    for (int k = 0; k < NF; ++k) senreg[k] = lds[OFF_R1 + tid * NFP + k];
    float senw1 = 0.f;
    #pragma unroll
    for (int k = 0; k < NF; ++k) senw1 += senreg[k] * W[k];
    lds[OFF_SW1 + tid] = senw1;
    __syncthreads();

    // ---------- pass 1: row stats (thread = row). S_row = qterm[j] + dot ----------
    float rm = -INFINITY, rs = 0.f;
    for (int jc = 0; jc < NCH; ++jc) {
        __syncthreads();   // previous chunk consumed
        for (int idx = tid; idx < JCH * (NF / 2); idx += 256) {
            int r = idx / (NF / 2);
            int c = idx - r * (NF / 2);
            float2 v = ((const float2*)query)[(jc * JCH + r) * (NF / 2) + c];
            v.x *= W[2 * NF + 2 * c];
            v.y *= W[2 * NF + 2 * c + 1];
            lds[OFF_CHS + r * NFP + 2 * c]     = v.x;
            lds[OFF_CHS + r * NFP + 2 * c + 1] = v.y;
        }
        __syncthreads();
        for (int jj = 0; jj < JCH; ++jj) {
            float dotv = dot50(senreg, &lds[OFF_CHS + jj * NFP]);
            float S = lds[OFF_QT + jc * JCH + jj] + dotv;
            float nm = fmaxf(rm, S);
            rs = rs * __expf(rm - nm) + __expf(S - nm);
            rm = nm;
        }
    }
    lds[OFF_RMAX + tid] = rm;
    lds[OFF_RINV + tid] = 1.f / rs;
    __syncthreads();

    // ---------- pass 2: columns (thread = col), col stats + t = Pq^T @ sen ----------
    for (int sp = 0; sp < 2; ++sp) {
        const int j = tid + sp * 256;
        float qsc[NF];
        #pragma unroll
        for (int k = 0; k < NF; ++k) qsc[k] = query[j * NF + k] * W[2 * NF + k];
        const float qtj = lds[OFF_QT + j];
        float cm = -INFINITY, cs = 0.f;
        float tacc[NF];
        #pragma unroll
        for (int k = 0; k < NF; ++k) tacc[k] = 0.f;

        for (int i = 0; i < ND; ++i) {
            float senb[NF];
            #pragma unroll
            for (int k = 0; k < NF; ++k) senb[k] = lds[OFF_R1 + i * NFP + k];
            float dotv = dot50(senb, qsc);
            // col stats on S_col = senw1[i] + dot  (qterm[j] cancels in col-softmax)
            float Sc = lds[OFF_SW1 + i] + dotv;
            float nm = fmaxf(cm, Sc);
            cs = cs * __expf(cm - nm) + __expf(Sc - nm);
            cm = nm;
            // Pq(i,j) (senw1[i] cancels in row-softmax)
            float pr = __expf(qtj + dotv - lds[OFF_RMAX + i]) * lds[OFF_RINV + i];
            #pragma unroll
            for (int k = 0; k < NF; ++k) tacc[k] += pr * senb[k];
        }
        lds[OFF_CMAX + j] = cm;
        lds[OFF_CINV + j] = 1.f / cs;
        if (sp == 0) {
            #pragma unroll
            for (int k = 0; k < NF; ++k) lds[OFF_R2 + tid * NFP + k] = tacc[k];
        } else {
            __syncthreads();  // all threads done reading sen region
            #pragma unroll
            for (int k = 0; k < NF; ++k) lds[OFF_R1 + tid * NFP + k] = tacc[k];
        }
    }
    __syncthreads();

    // ---------- pass 3: rows. aD2Q = Pd@query, aQ2D = Pd@t ----------
    float a1[NF], a2[NF];
    #pragma unroll
    for (int k = 0; k < NF; ++k) { a1[k] = 0.f; a2[k] = 0.f; }
    for (int jc = 0; jc < NCH; ++jc) {
        __syncthreads();
        for (int idx = tid; idx < JCH * (NF / 2); idx += 256) {
            int r = idx / (NF / 2);
            int c = idx - r * (NF / 2);
            float2 v = ((const float2*)query)[(jc * JCH + r) * (NF / 2) + c];
            lds[OFF_CHQ + r * NFP + 2 * c]     = v.x;
            lds[OFF_CHQ + r * NFP + 2 * c + 1] = v.y;
            v.x *= W[2 * NF + 2 * c];
            v.y *= W[2 * NF + 2 * c + 1];
            lds[OFF_CHS + r * NFP + 2 * c]     = v.x;
            lds[OFF_CHS + r * NFP + 2 * c + 1] = v.y;
        }
        __syncthreads();
        for (int jj = 0; jj < JCH; ++jj) {
            const int j = jc * JCH + jj;
            float dotv = dot50(senreg, &lds[OFF_CHS + jj * NFP]);
            float pc = __expf(senw1 + dotv - lds[OFF_CMAX + j]) * lds[OFF_CINV + j];
            const int tbase = (j < 256) ? (OFF_R2 + j * NFP) : (OFF_R1 + (j - 256) * NFP);
            #pragma unroll
            for (int k = 0; k < NF; ++k) a1[k] += pc * lds[OFF_CHQ + jj * NFP + k];
            #pragma unroll
            for (int k = 0; k < NF; ++k) a2[k] += pc * lds[tbase + k];
        }
    }

    // ---------- output: stage 32 rows at a time, coalesced float4 writes ----------
    const size_t outbase = (size_t)s * ND * 200;
    for (int g = 0; g < 8; ++g) {
        __syncthreads();
        if ((tid >> 5) == g) {
            const int rl = tid & 31;
            float* st = &lds[OFF_STAGE + rl * 200];
            #pragma unroll
            for (int k = 0; k < NF; ++k) {
                st[k]       = senreg[k];
                st[50 + k]  = a1[k];
                st[100 + k] = senreg[k] * a1[k];
                st[150 + k] = senreg[k] * a2[k];
            }
        }
        __syncthreads();
        float4* og = (float4*)(out + outbase + (size_t)g * 6400);
        const float4* sg = (const float4*)&lds[OFF_STAGE];
        for (int v = tid; v < 1600; v += 256) og[v] = sg[v];
    }
}

extern "C" void kernel_launch(void* const* d_in, const int* in_sizes, int n_in,
                              void* d_out, int out_size, void* d_ws, size_t ws_size,
                              hipStream_t stream) {
    const float* query = (const float*)d_in[0];
    const float* doc   = (const float*)d_in[1];
    const float* W     = (const float*)d_in[2];
    float* out = (float*)d_out;

    (void)d_ws; (void)ws_size; (void)n_in; (void)in_sizes; (void)out_size;

    hipFuncSetAttribute((const void*)cross_attn_kernel,
                        hipFuncAttributeMaxDynamicSharedMemorySize,
                        LDS_FLOATS * 4);
    cross_attn_kernel<<<dim3(512), dim3(256), LDS_FLOATS * 4, stream>>>(query, doc, W, out);
}

// Round 2
// 252.868 us; speedup vs baseline: 12.6128x; 12.6128x over previous
//
#include <hip/hip_runtime.h>
#include <math.h>

typedef __bf16 bf16_t;
typedef bf16_t bf16x8 __attribute__((ext_vector_type(8)));
typedef bf16_t bf16x4 __attribute__((ext_vector_type(4)));
typedef float f32x4 __attribute__((ext_vector_type(4)));

#define MFMA16(a,b,c) __builtin_amdgcn_mfma_f32_16x16x32_bf16((a),(b),(c),0,0,0)

#define ND 256
#define NQ 512
#define NF 50

// LDS element offsets (bf16 units unless noted)
#define SENT_E   0        // [64 f][264 i] bf16, stride 264
#define QW3T_E   16896    // [64 j][72 f]  bf16, stride 72
#define QTT_E    21504    // [64 f][72 j]  bf16, stride 72
#define PQ_E     26112    // [64 j][264 i] bf16, stride 264
#define PD_E     43008    // [256 i][72 j] bf16, stride 72
#define SENBF_E  PD_E     // alias (setup only): [256 i][72 f]
#define TT_E     61440    // [64 f][72 j]  bf16, stride 72
#define STATS_B  132096   // f32 area (bytes)
#define LDS_BYTES 142336

// stats f32 indices
#define ST_RMAX  0
#define ST_RSUM  256      // becomes rinv after pass 1
#define ST_CMAX  512
#define ST_CINV  1024
#define ST_CPART 1536
#define ST_QTERM 2048

__launch_bounds__(512, 2)
__global__ void ca_mfma_kernel(const float* __restrict__ query,
                               const float* __restrict__ doc,
                               const float* __restrict__ W,
                               float* __restrict__ out)
{
    extern __shared__ char smem[];
    bf16_t* lb = (bf16_t*)smem;
    float* stats = (float*)(smem + STATS_B);

    const int tid = threadIdx.x;
    const int w   = tid >> 6;
    const int l   = tid & 63;
    const int ln  = l & 15;
    const int lg  = l >> 4;
    const int s   = blockIdx.x;
    const float* sen_g = doc + (size_t)s * (ND * NF);

    // ---------------- setup ----------------
    // zero K-pad slots f=52..71 of SENBF and QW3T (K-dim safety incl. NaN)
    for (int e = tid; e < 256 * 20; e += 512) {
        int i = e / 20, f = 52 + (e - (e / 20) * 20);
        lb[SENBF_E + i * 72 + f] = (bf16_t)0.0f;
    }
    for (int e = tid; e < 64 * 20; e += 512) {
        int j = e / 20, f = 52 + (e - (e / 20) * 20);
        lb[QW3T_E + j * 72 + f] = (bf16_t)0.0f;
    }
    // doc -> SENBF [i][f] and SENT [f][i]
    for (int e = tid; e < ND * NF; e += 512) {
        int i = e / NF, f = e - i * NF;
        bf16_t b = (bf16_t)sen_g[e];
        lb[SENBF_E + i * 72 + f]  = b;
        lb[SENT_E + f * 264 + i]  = b;
    }
    // qterm[j] = q[j,:] . w2
    if (tid < NQ) {
        float acc = 0.f;
        #pragma unroll
        for (int f = 0; f < NF; ++f) acc += query[tid * NF + f] * W[NF + f];
        stats[ST_QTERM + tid] = acc;
    }
    // senw1 -> SENBF[i][51]; SENBF[i][50] = 1; init row stats
    if (tid < ND) {
        float acc = 0.f;
        #pragma unroll
        for (int f = 0; f < NF; ++f) acc += sen_g[tid * NF + f] * W[f];
        lb[SENBF_E + tid * 72 + 51] = (bf16_t)acc;
        lb[SENBF_E + tid * 72 + 50] = (bf16_t)1.0f;
        stats[ST_RMAX + tid] = -1e30f;
        stats[ST_RSUM + tid] = 0.f;
    }
    __syncthreads();

    // resident A-frags: sen rows (wave covers i = w*32 .. w*32+31)
    bf16x8 aS[2][2];
    #pragma unroll
    for (int mf = 0; mf < 2; ++mf)
        #pragma unroll
        for (int ks = 0; ks < 2; ++ks)
            aS[mf][ks] = *(bf16x8*)&lb[SENBF_E + (w * 32 + mf * 16 + ln) * 72 + lg * 8 + ks * 32];

    // ---------------- pass 1: stats ----------------
    for (int jt = 0; jt < 8; ++jt) {
        const int j0 = jt * 64;
        for (int e = tid; e < 64 * NF; e += 512) {
            int jj = e / NF, f = e - jj * NF;
            lb[QW3T_E + jj * 72 + f] = (bf16_t)(query[(j0 + jj) * NF + f] * W[2 * NF + f]);
        }
        if (tid < 128) {
            int jj = tid >> 1;
            if (tid & 1) lb[QW3T_E + jj * 72 + 51] = (bf16_t)1.0f;
            else         lb[QW3T_E + jj * 72 + 50] = (bf16_t)stats[ST_QTERM + j0 + jj];
        }
        __syncthreads();

        f32x4 acc[2][4];
        #pragma unroll
        for (int mf = 0; mf < 2; ++mf)
            #pragma unroll
            for (int nf = 0; nf < 4; ++nf)
                acc[mf][nf] = (f32x4){0.f, 0.f, 0.f, 0.f};
        #pragma unroll
        for (int ks = 0; ks < 2; ++ks) {
            #pragma unroll
            for (int nf = 0; nf < 4; ++nf) {
                bf16x8 b = *(bf16x8*)&lb[QW3T_E + (nf * 16 + ln) * 72 + lg * 8 + ks * 32];
                acc[0][nf] = MFMA16(aS[0][ks], b, acc[0][nf]);
                acc[1][nf] = MFMA16(aS[1][ks], b, acc[1][nf]);
            }
        }

        // col max (reduce over wave's 32 i, then cross-wave)
        float cmx0, cmx1, cmx2, cmx3;
        {
            float c[4];
            #pragma unroll
            for (int nf = 0; nf < 4; ++nf) {
                float m0 = fmaxf(fmaxf(acc[0][nf][0], acc[0][nf][1]), fmaxf(acc[0][nf][2], acc[0][nf][3]));
                float m1 = fmaxf(fmaxf(acc[1][nf][0], acc[1][nf][1]), fmaxf(acc[1][nf][2], acc[1][nf][3]));
                float m = fmaxf(m0, m1);
                m = fmaxf(m, __shfl_xor(m, 16));
                m = fmaxf(m, __shfl_xor(m, 32));
                c[nf] = m;
            }
            cmx0 = c[0]; cmx1 = c[1]; cmx2 = c[2]; cmx3 = c[3];
        }
        float selm = (lg < 2) ? ((lg == 0) ? cmx0 : cmx1) : ((lg == 2) ? cmx2 : cmx3);
        stats[ST_CPART + w * 64 + l] = selm;
        __syncthreads();
        if (tid < 64) {
            float m = stats[ST_CPART + tid];
            #pragma unroll
            for (int ww = 1; ww < 8; ++ww) m = fmaxf(m, stats[ST_CPART + ww * 64 + tid]);
            stats[ST_CMAX + j0 + tid] = m;
        }
        __syncthreads();
        // col sums
        {
            float c[4];
            #pragma unroll
            for (int nf = 0; nf < 4; ++nf) {
                float cm = stats[ST_CMAX + j0 + nf * 16 + ln];
                float ssum = 0.f;
                #pragma unroll
                for (int mf = 0; mf < 2; ++mf)
                    #pragma unroll
                    for (int r = 0; r < 4; ++r) ssum += __expf(acc[mf][nf][r] - cm);
                ssum += __shfl_xor(ssum, 16);
                ssum += __shfl_xor(ssum, 32);
                c[nf] = ssum;
            }
            float sel = (lg < 2) ? ((lg == 0) ? c[0] : c[1]) : ((lg == 2) ? c[2] : c[3]);
            stats[ST_CPART + w * 64 + l] = sel;
        }
        // row stats (online over tiles); disjoint i per wave -> race-free
        #pragma unroll
        for (int mf = 0; mf < 2; ++mf) {
            #pragma unroll
            for (int r = 0; r < 4; ++r) {
                float tm = fmaxf(fmaxf(acc[mf][0][r], acc[mf][1][r]), fmaxf(acc[mf][2][r], acc[mf][3][r]));
                tm = fmaxf(tm, __shfl_xor(tm, 1));
                tm = fmaxf(tm, __shfl_xor(tm, 2));
                tm = fmaxf(tm, __shfl_xor(tm, 4));
                tm = fmaxf(tm, __shfl_xor(tm, 8));
                float ts = __expf(acc[mf][0][r] - tm) + __expf(acc[mf][1][r] - tm)
                         + __expf(acc[mf][2][r] - tm) + __expf(acc[mf][3][r] - tm);
                ts += __shfl_xor(ts, 1);
                ts += __shfl_xor(ts, 2);
                ts += __shfl_xor(ts, 4);
                ts += __shfl_xor(ts, 8);
                if (ln == 0) {
                    int i = w * 32 + mf * 16 + lg * 4 + r;
                    float om = stats[ST_RMAX + i];
                    float nm = fmaxf(om, tm);
                    stats[ST_RSUM + i] = stats[ST_RSUM + i] * __expf(om - nm) + ts * __expf(tm - nm);
                    stats[ST_RMAX + i] = nm;
                }
            }
        }
        __syncthreads();
        if (tid < 64) {
            float ssum = 0.f;
            #pragma unroll
            for (int ww = 0; ww < 8; ++ww) ssum += stats[ST_CPART + ww * 64 + tid];
            stats[ST_CINV + j0 + tid] = 1.f / ssum;
        }
        __syncthreads();
    }
    if (tid < ND) stats[ST_RSUM + tid] = 1.f / stats[ST_RSUM + tid];  // rsum -> rinv
    __syncthreads();

    // ---------------- pass 2: P, t, outputs ----------------
    f32x4 accD[2][4], accQ[2][4];
    #pragma unroll
    for (int mf = 0; mf < 2; ++mf)
        #pragma unroll
        for (int nf = 0; nf < 4; ++nf) {
            accD[mf][nf] = (f32x4){0.f, 0.f, 0.f, 0.f};
            accQ[mf][nf] = (f32x4){0.f, 0.f, 0.f, 0.f};
        }

    for (int jt = 0; jt < 8; ++jt) {
        const int j0 = jt * 64;
        for (int e = tid; e < 64 * NF; e += 512) {
            int jj = e / NF, f = e - jj * NF;
            lb[QW3T_E + jj * 72 + f] = (bf16_t)(query[(j0 + jj) * NF + f] * W[2 * NF + f]);
        }
        if (tid < 128) {
            int jj = tid >> 1;
            if (tid & 1) lb[QW3T_E + jj * 72 + 51] = (bf16_t)1.0f;
            else         lb[QW3T_E + jj * 72 + 50] = (bf16_t)stats[ST_QTERM + j0 + jj];
        }
        for (int e = tid; e < 64 * NF; e += 512) {
            int f = e >> 6, jj = e & 63;
            lb[QTT_E + f * 72 + jj] = (bf16_t)query[(j0 + jj) * NF + f];
        }
        __syncthreads();

        // S tile recompute (bit-identical to pass 1)
        f32x4 acc[2][4];
        #pragma unroll
        for (int mf = 0; mf < 2; ++mf)
            #pragma unroll
            for (int nf = 0; nf < 4; ++nf)
                acc[mf][nf] = (f32x4){0.f, 0.f, 0.f, 0.f};
        #pragma unroll
        for (int ks = 0; ks < 2; ++ks) {
            #pragma unroll
            for (int nf = 0; nf < 4; ++nf) {
                bf16x8 b = *(bf16x8*)&lb[QW3T_E + (nf * 16 + ln) * 72 + lg * 8 + ks * 32];
                acc[0][nf] = MFMA16(aS[0][ks], b, acc[0][nf]);
                acc[1][nf] = MFMA16(aS[1][ks], b, acc[1][nf]);
            }
        }

        // Pq -> PQ[j][i] (b64 contiguous)
        #pragma unroll
        for (int mf = 0; mf < 2; ++mf) {
            const int ib = w * 32 + mf * 16 + lg * 4;
            float rm0 = stats[ST_RMAX + ib], rm1 = stats[ST_RMAX + ib + 1];
            float rm2 = stats[ST_RMAX + ib + 2], rm3 = stats[ST_RMAX + ib + 3];
            float ri0 = stats[ST_RSUM + ib], ri1 = stats[ST_RSUM + ib + 1];
            float ri2 = stats[ST_RSUM + ib + 2], ri3 = stats[ST_RSUM + ib + 3];
            #pragma unroll
            for (int nf = 0; nf < 4; ++nf) {
                bf16x4 pk;
                pk[0] = (bf16_t)(__expf(acc[mf][nf][0] - rm0) * ri0);
                pk[1] = (bf16_t)(__expf(acc[mf][nf][1] - rm1) * ri1);
                pk[2] = (bf16_t)(__expf(acc[mf][nf][2] - rm2) * ri2);
                pk[3] = (bf16_t)(__expf(acc[mf][nf][3] - rm3) * ri3);
                *(bf16x4*)&lb[PQ_E + (nf * 16 + ln) * 264 + ib] = pk;
            }
        }
        // Pd -> PD[i][j] (scattered b16)
        #pragma unroll
        for (int nf = 0; nf < 4; ++nf) {
            float cm = stats[ST_CMAX + j0 + nf * 16 + ln];
            float ci = stats[ST_CINV + j0 + nf * 16 + ln];
            #pragma unroll
            for (int mf = 0; mf < 2; ++mf) {
                const int ib = w * 32 + mf * 16 + lg * 4;
                #pragma unroll
                for (int r = 0; r < 4; ++r)
                    lb[PD_E + (ib + r) * 72 + nf * 16 + ln] = (bf16_t)(__expf(acc[mf][nf][r] - cm) * ci);
            }
        }
        __syncthreads();

        // t = Pq^T @ sen : wave w -> j-frag mt=w&3, f-frags nb,(nb+1), nb=(w>>2)*2
        {
            const int mt = w & 3, nb = (w >> 2) * 2;
            f32x4 t0 = (f32x4){0.f, 0.f, 0.f, 0.f}, t1 = (f32x4){0.f, 0.f, 0.f, 0.f};
            #pragma unroll
            for (int ks = 0; ks < 8; ++ks) {
                bf16x8 a  = *(bf16x8*)&lb[PQ_E + (mt * 16 + ln) * 264 + lg * 8 + ks * 32];
                bf16x8 b0 = *(bf16x8*)&lb[SENT_E + ((nb + 0) * 16 + ln) * 264 + lg * 8 + ks * 32];
                bf16x8 b1 = *(bf16x8*)&lb[SENT_E + ((nb + 1) * 16 + ln) * 264 + lg * 8 + ks * 32];
                t0 = MFMA16(a, b0, t0);
                t1 = MFMA16(a, b1, t1);
            }
            bf16x4 p0, p1;
            #pragma unroll
            for (int r = 0; r < 4; ++r) { p0[r] = (bf16_t)t0[r]; p1[r] = (bf16_t)t1[r]; }
            *(bf16x4*)&lb[TT_E + ((nb + 0) * 16 + ln) * 72 + mt * 16 + lg * 4] = p0;
            *(bf16x4*)&lb[TT_E + ((nb + 1) * 16 + ln) * 72 + mt * 16 + lg * 4] = p1;
        }
        __syncthreads();

        // aD2Q += Pd @ query ; aQ2D += Pd @ t
        #pragma unroll
        for (int ks = 0; ks < 2; ++ks) {
            bf16x8 aP0 = *(bf16x8*)&lb[PD_E + (w * 32 + 0 * 16 + ln) * 72 + lg * 8 + ks * 32];
            bf16x8 aP1 = *(bf16x8*)&lb[PD_E + (w * 32 + 1 * 16 + ln) * 72 + lg * 8 + ks * 32];
            #pragma unroll
            for (int nf = 0; nf < 4; ++nf) {
                bf16x8 bq = *(bf16x8*)&lb[QTT_E + (nf * 16 + ln) * 72 + lg * 8 + ks * 32];
                bf16x8 bt = *(bf16x8*)&lb[TT_E + (nf * 16 + ln) * 72 + lg * 8 + ks * 32];
                accD[0][nf] = MFMA16(aP0, bq, accD[0][nf]);
                accD[1][nf] = MFMA16(aP1, bq, accD[1][nf]);
                accQ[0][nf] = MFMA16(aP0, bt, accQ[0][nf]);
                accQ[1][nf] = MFMA16(aP1, bt, accQ[1][nf]);
            }
        }
        __syncthreads();
    }

    // ---------------- epilogue ----------------
    float* ea = (float*)(smem + 0);
    float* eb = (float*)(smem + 34816);
    #pragma unroll
    for (int c = 0; c < 2; ++c) {
        __syncthreads();
        if ((w >> 2) == c) {
            #pragma unroll
            for (int mf = 0; mf < 2; ++mf) {
                const int il = (w & 3) * 32 + mf * 16 + lg * 4;
                #pragma unroll
                for (int nf = 0; nf < 4; ++nf) {
                    const int f = nf * 16 + ln;
                    #pragma unroll
                    for (int r = 0; r < 4; ++r) {
                        ea[(il + r) * 68 + f] = accD[mf][nf][r];
                        eb[(il + r) * 68 + f] = accQ[mf][nf][r];
                    }
                }
            }
        }
        __syncthreads();
        for (int v = tid; v < 12800; v += 512) {
            int i = v / 100;
            int p = v - i * 100;
            int seg = p / 25;
            int f = (p - seg * 25) * 2;
            int gi = c * 128 + i;
            size_t ob = (size_t)s * (ND * 200) + (size_t)gi * 200 + seg * 50 + f;
            float2 o;
            if (seg == 0) {
                o = *(const float2*)&sen_g[gi * 50 + f];
            } else if (seg == 1) {
                o.x = ea[i * 68 + f]; o.y = ea[i * 68 + f + 1];
            } else if (seg == 2) {
                float2 d = *(const float2*)&sen_g[gi * 50 + f];
                o.x = d.x * ea[i * 68 + f]; o.y = d.y * ea[i * 68 + f + 1];
            } else {
                float2 d = *(const float2*)&sen_g[gi * 50 + f];
                o.x = d.x * eb[i * 68 + f]; o.y = d.y * eb[i * 68 + f + 1];
            }
            *(float2*)&out[ob] = o;
        }
    }
}

extern "C" void kernel_launch(void* const* d_in, const int* in_sizes, int n_in,
                              void* d_out, int out_size, void* d_ws, size_t ws_size,
                              hipStream_t stream) {
    const float* query = (const float*)d_in[0];
    const float* doc   = (const float*)d_in[1];
    const float* W     = (const float*)d_in[2];
    float* out = (float*)d_out;
    (void)d_ws; (void)ws_size; (void)n_in; (void)in_sizes; (void)out_size;

    hipFuncSetAttribute((const void*)ca_mfma_kernel,
                        hipFuncAttributeMaxDynamicSharedMemorySize,
                        LDS_BYTES);
    ca_mfma_kernel<<<dim3(512), dim3(512), LDS_BYTES, stream>>>(query, doc, W, out);
}

// Round 3
// 207.418 us; speedup vs baseline: 15.3766x; 1.2191x over previous
//
#include <hip/hip_runtime.h>
#include <math.h>

typedef __bf16 bf16_t;
typedef bf16_t bf16x2 __attribute__((ext_vector_type(2)));
typedef bf16_t bf16x4 __attribute__((ext_vector_type(4)));
typedef bf16_t bf16x8 __attribute__((ext_vector_type(8)));
typedef float f32x4 __attribute__((ext_vector_type(4)));

#define MFMA16(a,b,c) __builtin_amdgcn_mfma_f32_16x16x32_bf16((a),(b),(c),0,0,0)

#define ND 256
#define NQ 512
#define NF 50
#define L2E 1.44269504f

// LDS bf16-element offsets
#define SENT_E 0        // [64 f][264 i]   33792 B  (rows 50..63 zeroed)
#define PD_E   16896    // [256 i][72 j]   36864 B  (setup alias: sen [i][f])
#define PQ_E   35328    // [64 j][264 i]   33792 B  (pass1 alias: col partials)
#define TT_E   52224    // [64 f][72 j]     9216 B
#define QW3_E  56832    // 2x [64 j][72 f] 18432 B
#define QTT_E  66048    // 2x [64 f][72 j] 18432 B
#define STATS_B 150528  // f32 qterm[512], cmax[512], cinv[512]
#define PART_B  70656   // bytes (= PQ region), float2 2x[16 w][64 j]
#define LDS_BYTES 156672

#define ST_QTERM 0
#define ST_CMAX  512
#define ST_CINV  1024

__launch_bounds__(1024, 4)
__global__ void ca2_kernel(const float* __restrict__ query,
                           const float* __restrict__ doc,
                           const float* __restrict__ W,
                           float* __restrict__ out)
{
    extern __shared__ char smem[];
    bf16_t* lb = (bf16_t*)smem;
    float* stats = (float*)(smem + STATS_B);
    float2* part = (float2*)(smem + PART_B);

    const int tid = threadIdx.x;
    const int w = tid >> 6, l = tid & 63, ln = l & 15, lg = l >> 4;
    const int s = blockIdx.x;
    const float* sen_g = doc + (size_t)s * (ND * NF);

    // ---------------- setup ----------------
    for (int e = tid; e < 14 * 264; e += 1024) {           // SENT pad rows -> 0
        int f = e / 264, i = e - f * 264;
        lb[SENT_E + (50 + f) * 264 + i] = (bf16_t)0.f;
    }
    for (int e = tid; e < 256 * 12; e += 1024) {           // sen K-pad cols -> 0
        int i = e / 12, f = e - i * 12;
        lb[PD_E + i * 72 + 52 + f] = (bf16_t)0.f;
    }
    for (int e = tid; e < 256 * 25; e += 1024) {           // doc -> sen[i][f] + sen^T
        int i = e / 25, c = e - i * 25;
        float2 v = ((const float2*)sen_g)[i * 25 + c];
        bf16x2 p; p[0] = (bf16_t)v.x; p[1] = (bf16_t)v.y;
        *(bf16x2*)&lb[PD_E + i * 72 + 2 * c] = p;
        lb[SENT_E + (2 * c) * 264 + i]     = p[0];
        lb[SENT_E + (2 * c + 1) * 264 + i] = p[1];
    }
    if (tid < NQ) {                                        // qterm = q . w2
        float acc = 0.f;
        #pragma unroll
        for (int c = 0; c < 25; ++c) {
            float2 v = ((const float2*)query)[tid * 25 + c];
            acc += v.x * W[NF + 2 * c] + v.y * W[NF + 2 * c + 1];
        }
        stats[ST_QTERM + tid] = acc;
    }
    if (tid < ND) {                                        // bias cols: 1, senw1
        float acc = 0.f;
        #pragma unroll
        for (int f = 0; f < NF; ++f) acc += sen_g[tid * NF + f] * W[f];
        lb[PD_E + tid * 72 + 50] = (bf16_t)1.0f;
        lb[PD_E + tid * 72 + 51] = (bf16_t)acc;
    }
    __syncthreads();

    // resident sen A-frags (wave owns i = w*16 .. w*16+15)
    bf16x8 aS[2];
    #pragma unroll
    for (int ks = 0; ks < 2; ++ks)
        aS[ks] = *(bf16x8*)&lb[PD_E + (w * 16 + ln) * 72 + lg * 8 + ks * 32];

    auto stageQW3 = [&](int jt, int buf) {   // [j][f] = q*w3*log2e + bias slots
        const int j0 = jt * 64;
        bf16_t* dst = lb + QW3_E + buf * 4608;
        for (int e = tid; e < 1600; e += 1024) {
            int jj = e / 25, c = e - jj * 25;
            float2 v = ((const float2*)query)[(j0 + jj) * 25 + c];
            bf16x2 p;
            p[0] = (bf16_t)(v.x * W[2 * NF + 2 * c] * L2E);
            p[1] = (bf16_t)(v.y * W[2 * NF + 2 * c + 1] * L2E);
            *(bf16x2*)&dst[jj * 72 + 2 * c] = p;
        }
        if (tid < 64) {
            dst[tid * 72 + 50] = (bf16_t)(stats[ST_QTERM + j0 + tid] * L2E);
            dst[tid * 72 + 51] = (bf16_t)L2E;
            #pragma unroll
            for (int f = 52; f < 64; ++f) dst[tid * 72 + f] = (bf16_t)0.f;
        }
    };
    auto stageQTT = [&](int jt, int buf) {   // [f][j] = q^T
        const int j0 = jt * 64;
        bf16_t* dst = lb + QTT_E + buf * 4608;
        for (int e = tid; e < 1600; e += 1024) {
            int c = e >> 6, jj = e & 63;
            float2 v = ((const float2*)query)[(j0 + jj) * 25 + c];
            dst[(2 * c) * 72 + jj]     = (bf16_t)v.x;
            dst[(2 * c + 1) * 72 + jj] = (bf16_t)v.y;
        }
    };

    // ---------------- pass 1: stats, 1 barrier/tile ----------------
    float rm[4], rs[4];
    #pragma unroll
    for (int r = 0; r < 4; ++r) { rm[r] = -1e30f; rs[r] = 0.f; }

    stageQW3(0, 0);
    __syncthreads();

    for (int jt = 0; jt < 8; ++jt) {
        if (jt < 7) stageQW3(jt + 1, (jt + 1) & 1);
        const bf16_t* qb = lb + QW3_E + (jt & 1) * 4608;
        f32x4 acc[4];
        #pragma unroll
        for (int nf = 0; nf < 4; ++nf) acc[nf] = (f32x4){0.f, 0.f, 0.f, 0.f};
        #pragma unroll
        for (int ks = 0; ks < 2; ++ks)
            #pragma unroll
            for (int nf = 0; nf < 4; ++nf) {
                bf16x8 b = *(bf16x8*)&qb[(nf * 16 + ln) * 72 + lg * 8 + ks * 32];
                acc[nf] = MFMA16(aS[ks], b, acc[nf]);
            }
        // col partials (over this wave's 16 i)
        #pragma unroll
        for (int nf = 0; nf < 4; ++nf) {
            float m = fmaxf(fmaxf(acc[nf][0], acc[nf][1]), fmaxf(acc[nf][2], acc[nf][3]));
            m = fmaxf(m, __shfl_xor(m, 16));
            m = fmaxf(m, __shfl_xor(m, 32));
            float ss = exp2f(acc[nf][0] - m) + exp2f(acc[nf][1] - m)
                     + exp2f(acc[nf][2] - m) + exp2f(acc[nf][3] - m);
            ss += __shfl_xor(ss, 16);
            ss += __shfl_xor(ss, 32);
            if (lg == 0) part[(jt & 1) * 1024 + w * 64 + nf * 16 + ln] = make_float2(m, ss);
        }
        // row stats fully in registers (online across tiles)
        #pragma unroll
        for (int r = 0; r < 4; ++r) {
            float m = fmaxf(fmaxf(acc[0][r], acc[1][r]), fmaxf(acc[2][r], acc[3][r]));
            m = fmaxf(m, __shfl_xor(m, 1));
            m = fmaxf(m, __shfl_xor(m, 2));
            m = fmaxf(m, __shfl_xor(m, 4));
            m = fmaxf(m, __shfl_xor(m, 8));
            float ss = exp2f(acc[0][r] - m) + exp2f(acc[1][r] - m)
                     + exp2f(acc[2][r] - m) + exp2f(acc[3][r] - m);
            ss += __shfl_xor(ss, 1);
            ss += __shfl_xor(ss, 2);
            ss += __shfl_xor(ss, 4);
            ss += __shfl_xor(ss, 8);
            float nm = fmaxf(rm[r], m);
            rs[r] = rs[r] * exp2f(rm[r] - nm) + ss * exp2f(m - nm);
            rm[r] = nm;
        }
        __syncthreads();
        // merge col partials (overlaps next tile's compute on other waves)
        if (tid < 64) {
            const float2* pp = part + (jt & 1) * 1024;
            float2 v0 = pp[tid];
            float M = v0.x, S = v0.y;
            #pragma unroll
            for (int ww = 1; ww < 16; ++ww) {
                float2 v = pp[ww * 64 + tid];
                float nm = fmaxf(M, v.x);
                S = S * exp2f(M - nm) + v.y * exp2f(v.x - nm);
                M = nm;
            }
            stats[ST_CMAX + jt * 64 + tid] = M;
            stats[ST_CINV + jt * 64 + tid] = 1.f / S;
        }
    }

    float ri[4];
    #pragma unroll
    for (int r = 0; r < 4; ++r) ri[r] = 1.f / rs[r];

    // ---------------- pass 2 ----------------
    f32x4 accD[4], accQ[4];
    #pragma unroll
    for (int nf = 0; nf < 4; ++nf) {
        accD[nf] = (f32x4){0.f, 0.f, 0.f, 0.f};
        accQ[nf] = (f32x4){0.f, 0.f, 0.f, 0.f};
    }
    const int mt = w & 3, nt = w >> 2;

    stageQW3(0, 0);
    stageQTT(0, 0);
    __syncthreads();

    for (int jt = 0; jt < 8; ++jt) {
        // phase A: stage next, recompute S (bit-identical), write Pq/Pd
        if (jt < 7) { stageQW3(jt + 1, (jt + 1) & 1); stageQTT(jt + 1, (jt + 1) & 1); }
        const bf16_t* qb = lb + QW3_E + (jt & 1) * 4608;
        f32x4 acc[4];
        #pragma unroll
        for (int nf = 0; nf < 4; ++nf) acc[nf] = (f32x4){0.f, 0.f, 0.f, 0.f};
        #pragma unroll
        for (int ks = 0; ks < 2; ++ks)
            #pragma unroll
            for (int nf = 0; nf < 4; ++nf) {
                bf16x8 b = *(bf16x8*)&qb[(nf * 16 + ln) * 72 + lg * 8 + ks * 32];
                acc[nf] = MFMA16(aS[ks], b, acc[nf]);
            }
        #pragma unroll
        for (int nf = 0; nf < 4; ++nf) {
            float cm = stats[ST_CMAX + jt * 64 + nf * 16 + ln];
            float ci = stats[ST_CINV + jt * 64 + nf * 16 + ln];
            bf16x4 pk;
            #pragma unroll
            for (int r = 0; r < 4; ++r) pk[r] = (bf16_t)(exp2f(acc[nf][r] - rm[r]) * ri[r]);
            *(bf16x4*)&lb[PQ_E + (nf * 16 + ln) * 264 + w * 16 + lg * 4] = pk;
            #pragma unroll
            for (int r = 0; r < 4; ++r)
                lb[PD_E + (w * 16 + lg * 4 + r) * 72 + nf * 16 + ln] =
                    (bf16_t)(exp2f(acc[nf][r] - cm) * ci);
        }
        __syncthreads();

        // phase B: t = Pq^T@sen (1 frag/wave) + accD = Pd@query
        f32x4 tacc = (f32x4){0.f, 0.f, 0.f, 0.f};
        #pragma unroll
        for (int ks = 0; ks < 8; ++ks) {
            bf16x8 a = *(bf16x8*)&lb[PQ_E + (mt * 16 + ln) * 264 + lg * 8 + ks * 32];
            bf16x8 b = *(bf16x8*)&lb[SENT_E + (nt * 16 + ln) * 264 + lg * 8 + ks * 32];
            tacc = MFMA16(a, b, tacc);
        }
        const bf16_t* qt = lb + QTT_E + (jt & 1) * 4608;
        bf16x8 aP[2];
        #pragma unroll
        for (int ks = 0; ks < 2; ++ks) {
            aP[ks] = *(bf16x8*)&lb[PD_E + (w * 16 + ln) * 72 + lg * 8 + ks * 32];
            #pragma unroll
            for (int nf = 0; nf < 4; ++nf) {
                bf16x8 bq = *(bf16x8*)&qt[(nf * 16 + ln) * 72 + lg * 8 + ks * 32];
                accD[nf] = MFMA16(aP[ks], bq, accD[nf]);
            }
        }
        bf16x4 tk;
        #pragma unroll
        for (int r = 0; r < 4; ++r) tk[r] = (bf16_t)tacc[r];
        *(bf16x4*)&lb[TT_E + (nt * 16 + ln) * 72 + mt * 16 + lg * 4] = tk;
        __syncthreads();

        // phase C: accQ = Pd @ t
        #pragma unroll
        for (int ks = 0; ks < 2; ++ks)
            #pragma unroll
            for (int nf = 0; nf < 4; ++nf) {
                bf16x8 bt = *(bf16x8*)&lb[TT_E + (nf * 16 + ln) * 72 + lg * 8 + ks * 32];
                accQ[nf] = MFMA16(aP[ks], bt, accQ[nf]);
            }
        __syncthreads();
    }

    // ---------------- epilogue ----------------
    float* ea = (float*)smem;                 // [256][68] f32
    float* eb = (float*)(smem + 69632);
    #pragma unroll
    for (int nf = 0; nf < 4; ++nf)
        #pragma unroll
        for (int r = 0; r < 4; ++r) {
            ea[(w * 16 + lg * 4 + r) * 68 + nf * 16 + ln] = accD[nf][r];
            eb[(w * 16 + lg * 4 + r) * 68 + nf * 16 + ln] = accQ[nf][r];
        }
    __syncthreads();
    const size_t ob0 = (size_t)s * (ND * 200);
    for (int v = tid; v < 25600; v += 1024) {
        int i = v / 100;
        int p = v - i * 100;
        int seg = p / 25;
        int f = (p - seg * 25) * 2;
        float2 o;
        if (seg == 0) {
            o = *(const float2*)&sen_g[i * 50 + f];
        } else if (seg == 1) {
            o.x = ea[i * 68 + f]; o.y = ea[i * 68 + f + 1];
        } else if (seg == 2) {
            float2 d = *(const float2*)&sen_g[i * 50 + f];
            o.x = d.x * ea[i * 68 + f]; o.y = d.y * ea[i * 68 + f + 1];
        } else {
            float2 d = *(const float2*)&sen_g[i * 50 + f];
            o.x = d.x * eb[i * 68 + f]; o.y = d.y * eb[i * 68 + f + 1];
        }
        *(float2*)&out[ob0 + (size_t)i * 200 + seg * 50 + f] = o;
    }
}

extern "C" void kernel_launch(void* const* d_in, const int* in_sizes, int n_in,
                              void* d_out, int out_size, void* d_ws, size_t ws_size,
                              hipStream_t stream) {
    const float* query = (const float*)d_in[0];
    const float* doc   = (const float*)d_in[1];
    const float* W     = (const float*)d_in[2];
    float* out = (float*)d_out;
    (void)d_ws; (void)ws_size; (void)n_in; (void)in_sizes; (void)out_size;

    hipFuncSetAttribute((const void*)ca2_kernel,
                        hipFuncAttributeMaxDynamicSharedMemorySize,
                        LDS_BYTES);
    ca2_kernel<<<dim3(512), dim3(1024), LDS_BYTES, stream>>>(query, doc, W, out);
}

// Round 4
// 151.664 us; speedup vs baseline: 21.0292x; 1.3676x over previous
//
#include <hip/hip_runtime.h>
#include <math.h>

typedef __bf16 bf16_t;
typedef bf16_t bf16x2 __attribute__((ext_vector_type(2)));
typedef bf16_t bf16x4 __attribute__((ext_vector_type(4)));
typedef bf16_t bf16x8 __attribute__((ext_vector_type(8)));
typedef float f32x4 __attribute__((ext_vector_type(4)));

#define MFMA16(a,b,c) __builtin_amdgcn_mfma_f32_16x16x32_bf16((a),(b),(c),0,0,0)

#define ND 256
#define NQ 512
#define NF 50
#define L2E 1.44269504f
#define SHIFT 64.0f

// bf16-element offsets
#define SENT_E 0        // [64 f][264 i]  (rows 50..63 zero; ri-scaled after pass1)
#define PD_E   16896    // [256 i][72 j]  (setup alias sen[i][f]+bias; pass2 raw E)
#define PQ_E   35328    // [64 j][264 i]  (pass1 alias: f32 col partials [8][16][64])
#define TT_E   52224    // 2 x [64 f][72 j]  (t * ci, bf16)
#define QW3_E  61440    // 2 x [64 j][72 f]  (q*w3*L2E + bias; cols 52..63 zero)
#define QTT_E  70656    // [64 f][72 j]      (q^T * ci; rows 50..63 zero)
#define STATS_B 150528
#define PART_B  70656   // bytes (= PQ region)
#define LDS_BYTES 155648

#define ST_QTERM 0
#define ST_CINV  512
#define ST_RINV  1024

__launch_bounds__(1024, 1)
__global__ void ca3_kernel(const float* __restrict__ query,
                           const float* __restrict__ doc,
                           const float* __restrict__ W,
                           float* __restrict__ out)
{
    extern __shared__ char smem[];
    bf16_t* lb = (bf16_t*)smem;
    float* stats = (float*)(smem + STATS_B);
    float* part  = (float*)(smem + PART_B);

    const int tid = threadIdx.x;
    const int w = tid >> 6, l = tid & 63, ln = l & 15, lg = l >> 4;
    const int s = blockIdx.x;
    const float* sen_g = doc + (size_t)s * (ND * NF);

    // ---------------- setup ----------------
    for (int e = tid; e < 14 * 264; e += 1024) {          // SENT pad rows
        int f = e / 264, i = e - f * 264;
        lb[SENT_E + (50 + f) * 264 + i] = (bf16_t)0.f;
    }
    for (int e = tid; e < 256 * 12; e += 1024) {          // sen K-pad cols
        int i = e / 12, f = e - i * 12;
        lb[PD_E + i * 72 + 52 + f] = (bf16_t)0.f;
    }
    for (int e = tid; e < 2 * 64 * 12; e += 1024) {       // QW3 pad cols (both bufs)
        int b = e / 768, r2 = e - b * 768;
        int jj = r2 / 12, f = 52 + (r2 - jj * 12);
        lb[QW3_E + b * 4608 + jj * 72 + f] = (bf16_t)0.f;
    }
    for (int e = tid; e < 14 * 72; e += 1024) {           // QTT pad rows
        int f = e / 72, j = e - f * 72;
        lb[QTT_E + (50 + f) * 72 + j] = (bf16_t)0.f;
    }
    for (int e = tid; e < 256 * 25; e += 1024) {          // doc -> sen[i][f] + sen^T
        int i = e / 25, c = e - i * 25;
        float2 v = ((const float2*)sen_g)[i * 25 + c];
        bf16x2 p; p[0] = (bf16_t)v.x; p[1] = (bf16_t)v.y;
        *(bf16x2*)&lb[PD_E + i * 72 + 2 * c] = p;
        lb[SENT_E + (2 * c) * 264 + i]     = p[0];
        lb[SENT_E + (2 * c + 1) * 264 + i] = p[1];
    }
    if (tid < NQ) {                                       // qterm = q . w2
        float acc = 0.f;
        #pragma unroll
        for (int c = 0; c < 25; ++c) {
            float2 v = ((const float2*)query)[tid * 25 + c];
            acc += v.x * W[NF + 2 * c] + v.y * W[NF + 2 * c + 1];
        }
        stats[ST_QTERM + tid] = acc;
    }
    if (tid < ND) {                                       // bias cols: 1, senw1
        float acc = 0.f;
        #pragma unroll
        for (int f = 0; f < NF; ++f) acc += sen_g[tid * NF + f] * W[f];
        lb[PD_E + tid * 72 + 50] = (bf16_t)1.0f;
        lb[PD_E + tid * 72 + 51] = (bf16_t)acc;
    }
    __syncthreads();

    bf16x8 aS[2];
    #pragma unroll
    for (int ks = 0; ks < 2; ++ks)
        aS[ks] = *(bf16x8*)&lb[PD_E + (w * 16 + ln) * 72 + lg * 8 + ks * 32];

    auto stageQW3 = [&](int jt, int buf) {
        const int j0 = jt * 64;
        bf16_t* dst = lb + QW3_E + buf * 4608;
        for (int e = tid; e < 1600; e += 1024) {
            int jj = e / 25, c = e - jj * 25;
            float2 v = ((const float2*)query)[(j0 + jj) * 25 + c];
            bf16x2 p;
            p[0] = (bf16_t)(v.x * W[2 * NF + 2 * c] * L2E);
            p[1] = (bf16_t)(v.y * W[2 * NF + 2 * c + 1] * L2E);
            *(bf16x2*)&dst[jj * 72 + 2 * c] = p;
        }
        if (tid < 64) {
            dst[tid * 72 + 50] = (bf16_t)(stats[ST_QTERM + j0 + tid] * L2E);
            dst[tid * 72 + 51] = (bf16_t)L2E;
        }
    };
    auto stageQTT = [&](int jt) {    // q^T scaled by cinv[j]
        const int j0 = jt * 64;
        for (int e = tid; e < 1600; e += 1024) {
            int c = e >> 6, jj = e & 63;
            float ci = stats[ST_CINV + j0 + jj];
            float2 v = ((const float2*)query)[(j0 + jj) * 25 + c];
            lb[QTT_E + (2 * c) * 72 + jj]     = (bf16_t)(v.x * ci);
            lb[QTT_E + (2 * c + 1) * 72 + jj] = (bf16_t)(v.y * ci);
        }
    };

    // ---------------- pass 1: sums only (no max) ----------------
    float rpart[4] = {0.f, 0.f, 0.f, 0.f};
    stageQW3(0, 0);
    __syncthreads();

    for (int jt = 0; jt < 8; ++jt) {
        if (jt < 7) stageQW3(jt + 1, (jt + 1) & 1);
        const bf16_t* qb = lb + QW3_E + (jt & 1) * 4608;
        f32x4 acc[4];
        #pragma unroll
        for (int nf = 0; nf < 4; ++nf) acc[nf] = (f32x4){-SHIFT, -SHIFT, -SHIFT, -SHIFT};
        #pragma unroll
        for (int ks = 0; ks < 2; ++ks)
            #pragma unroll
            for (int nf = 0; nf < 4; ++nf) {
                bf16x8 b = *(bf16x8*)&qb[(nf * 16 + ln) * 72 + lg * 8 + ks * 32];
                acc[nf] = MFMA16(aS[ks], b, acc[nf]);
            }
        #pragma unroll
        for (int nf = 0; nf < 4; ++nf) {
            float e0 = exp2f(acc[nf][0]), e1 = exp2f(acc[nf][1]);
            float e2 = exp2f(acc[nf][2]), e3 = exp2f(acc[nf][3]);
            rpart[0] += e0; rpart[1] += e1; rpart[2] += e2; rpart[3] += e3;
            float c = (e0 + e1) + (e2 + e3);
            c += __shfl_xor(c, 16);
            c += __shfl_xor(c, 32);
            if (lg == 0) part[jt * 1024 + w * 64 + nf * 16 + ln] = c;
        }
        __syncthreads();
    }
    // row sums -> rinv (one-time reduce over ln)
    #pragma unroll
    for (int r = 0; r < 4; ++r) {
        float v = rpart[r];
        v += __shfl_xor(v, 1);
        v += __shfl_xor(v, 2);
        v += __shfl_xor(v, 4);
        v += __shfl_xor(v, 8);
        if (ln == 0) stats[ST_RINV + w * 16 + lg * 4 + r] = 1.f / v;
    }
    __syncthreads();
    // col merge (adds only) + SENT *= rinv (fold ri into sen)
    if (tid < 512) {
        const float* pp = part + (tid >> 6) * 1024 + (tid & 63);
        float ssum = 0.f;
        #pragma unroll
        for (int ww = 0; ww < 16; ++ww) ssum += pp[ww * 64];
        stats[ST_CINV + tid] = 1.f / ssum;
    }
    {
        const int i = tid & 255;
        const float rv = stats[ST_RINV + i];
        for (int f = tid >> 8; f < 50; f += 4)
            lb[SENT_E + f * 264 + i] = (bf16_t)((float)lb[SENT_E + f * 264 + i] * rv);
    }
    __syncthreads();

    // ---------------- pass 2 ----------------
    f32x4 accD[4], accQ[4];
    #pragma unroll
    for (int nf = 0; nf < 4; ++nf) {
        accD[nf] = (f32x4){0.f, 0.f, 0.f, 0.f};
        accQ[nf] = (f32x4){0.f, 0.f, 0.f, 0.f};
    }
    bf16x8 aP[2];
    const int mt = w & 3, nt = w >> 2;

    stageQW3(0, 0);
    __syncthreads();

    for (int jt = 0; jt < 8; ++jt) {
        // accQ for previous tile (aP regs + TT[(jt-1)&1])
        if (jt > 0) {
            const bf16_t* tt = lb + TT_E + ((jt - 1) & 1) * 4608;
            #pragma unroll
            for (int ks = 0; ks < 2; ++ks)
                #pragma unroll
                for (int nf = 0; nf < 4; ++nf) {
                    bf16x8 bt = *(bf16x8*)&tt[(nf * 16 + ln) * 72 + lg * 8 + ks * 32];
                    accQ[nf] = MFMA16(aP[ks], bt, accQ[nf]);
                }
        }
        if (jt < 7) stageQW3(jt + 1, (jt + 1) & 1);
        stageQTT(jt);
        const bf16_t* qb = lb + QW3_E + (jt & 1) * 4608;
        f32x4 acc[4];
        #pragma unroll
        for (int nf = 0; nf < 4; ++nf) acc[nf] = (f32x4){-SHIFT, -SHIFT, -SHIFT, -SHIFT};
        #pragma unroll
        for (int ks = 0; ks < 2; ++ks)
            #pragma unroll
            for (int nf = 0; nf < 4; ++nf) {
                bf16x8 b = *(bf16x8*)&qb[(nf * 16 + ln) * 72 + lg * 8 + ks * 32];
                acc[nf] = MFMA16(aS[ks], b, acc[nf]);
            }
        // raw E -> PQ [j][i] (b64) and PD [i][j] (b16)
        #pragma unroll
        for (int nf = 0; nf < 4; ++nf) {
            bf16x4 pk;
            pk[0] = (bf16_t)exp2f(acc[nf][0]);
            pk[1] = (bf16_t)exp2f(acc[nf][1]);
            pk[2] = (bf16_t)exp2f(acc[nf][2]);
            pk[3] = (bf16_t)exp2f(acc[nf][3]);
            *(bf16x4*)&lb[PQ_E + (nf * 16 + ln) * 264 + w * 16 + lg * 4] = pk;
            #pragma unroll
            for (int r = 0; r < 4; ++r)
                lb[PD_E + (w * 16 + lg * 4 + r) * 72 + nf * 16 + ln] = pk[r];
        }
        __syncthreads();

        // t = E^T @ sen_r  (one frag/wave), scaled by ci at write
        f32x4 tacc = (f32x4){0.f, 0.f, 0.f, 0.f};
        #pragma unroll
        for (int ks = 0; ks < 8; ++ks) {
            bf16x8 a = *(bf16x8*)&lb[PQ_E + (mt * 16 + ln) * 264 + lg * 8 + ks * 32];
            bf16x8 b = *(bf16x8*)&lb[SENT_E + (nt * 16 + ln) * 264 + lg * 8 + ks * 32];
            tacc = MFMA16(a, b, tacc);
        }
        bf16x4 tk;
        #pragma unroll
        for (int r = 0; r < 4; ++r)
            tk[r] = (bf16_t)(tacc[r] * stats[ST_CINV + jt * 64 + mt * 16 + lg * 4 + r]);
        *(bf16x4*)&lb[TT_E + (jt & 1) * 4608 + (nt * 16 + ln) * 72 + mt * 16 + lg * 4] = tk;

        // accD = E @ (q*ci)^T
        #pragma unroll
        for (int ks = 0; ks < 2; ++ks) {
            aP[ks] = *(bf16x8*)&lb[PD_E + (w * 16 + ln) * 72 + lg * 8 + ks * 32];
            #pragma unroll
            for (int nf = 0; nf < 4; ++nf) {
                bf16x8 bq = *(bf16x8*)&lb[QTT_E + (nf * 16 + ln) * 72 + lg * 8 + ks * 32];
                accD[nf] = MFMA16(aP[ks], bq, accD[nf]);
            }
        }
        __syncthreads();
    }
    // final accQ (tile 7, TT buf 1)
    {
        const bf16_t* tt = lb + TT_E + 4608;
        #pragma unroll
        for (int ks = 0; ks < 2; ++ks)
            #pragma unroll
            for (int nf = 0; nf < 4; ++nf) {
                bf16x8 bt = *(bf16x8*)&tt[(nf * 16 + ln) * 72 + lg * 8 + ks * 32];
                accQ[nf] = MFMA16(aP[ks], bt, accQ[nf]);
            }
    }
    __syncthreads();   // protect TT before epilogue overwrites LDS

    // ---------------- epilogue ----------------
    float* ea = (float*)smem;                  // [256][68]
    float* eb = (float*)(smem + 69632);
    #pragma unroll
    for (int nf = 0; nf < 4; ++nf)
        #pragma unroll
        for (int r = 0; r < 4; ++r) {
            ea[(w * 16 + lg * 4 + r) * 68 + nf * 16 + ln] = accD[nf][r];
            eb[(w * 16 + lg * 4 + r) * 68 + nf * 16 + ln] = accQ[nf][r];
        }
    __syncthreads();
    const size_t ob0 = (size_t)s * (ND * 200);
    for (int v = tid; v < 25600; v += 1024) {
        int i = v / 100;
        int p = v - i * 100;
        int seg = p / 25;
        int f = (p - seg * 25) * 2;
        float2 o;
        if (seg == 0) {
            o = *(const float2*)&sen_g[i * 50 + f];
        } else if (seg == 1) {
            o.x = ea[i * 68 + f]; o.y = ea[i * 68 + f + 1];
        } else if (seg == 2) {
            float2 d = *(const float2*)&sen_g[i * 50 + f];
            o.x = d.x * ea[i * 68 + f]; o.y = d.y * ea[i * 68 + f + 1];
        } else {
            float2 d = *(const float2*)&sen_g[i * 50 + f];
            o.x = d.x * eb[i * 68 + f]; o.y = d.y * eb[i * 68 + f + 1];
        }
        *(float2*)&out[ob0 + (size_t)i * 200 + seg * 50 + f] = o;
    }
}

extern "C" void kernel_launch(void* const* d_in, const int* in_sizes, int n_in,
                              void* d_out, int out_size, void* d_ws, size_t ws_size,
                              hipStream_t stream) {
    const float* query = (const float*)d_in[0];
    const float* doc   = (const float*)d_in[1];
    const float* W     = (const float*)d_in[2];
    float* out = (float*)d_out;
    (void)d_ws; (void)ws_size; (void)n_in; (void)in_sizes; (void)out_size;

    hipFuncSetAttribute((const void*)ca3_kernel,
                        hipFuncAttributeMaxDynamicSharedMemorySize,
                        LDS_BYTES);
    ca3_kernel<<<dim3(512), dim3(1024), LDS_BYTES, stream>>>(query, doc, W, out);
}